// Round 9
// baseline (705.850 us; speedup 1.0000x reference)
//
#include <hip/hip_runtime.h>
#include <hip/hip_bf16.h>
#include <hip/hip_cooperative_groups.h>

namespace cg = cooperative_groups;

#define N_NODES 100000
#define N_EDGES 600000
#define N_LABELS 200000
#define DIM 128
#define NPARTS 391           // ceil(N_NODES/256)
#define NT_TILES 6250        // N_NODES / 16 exactly
#define GEMM_GRID 512        // fallback gemm grid
#define MAX_COOP_GRID 2048   // 8 blocks/CU at 64 VGPR

using short8 = __attribute__((ext_vector_type(8))) short;
using f32x2  = __attribute__((ext_vector_type(2))) float;
using f32x4  = __attribute__((ext_vector_type(4))) float;
using u32x2  = __attribute__((ext_vector_type(2))) unsigned;
using u32x4  = __attribute__((ext_vector_type(4))) unsigned;

__device__ __forceinline__ float b2f(short s) {
    union { unsigned u; float f; } c;
    c.u = ((unsigned)(unsigned short)s) << 16;
    return c.f;
}
__device__ __forceinline__ f32x2 b2f2(unsigned u) {
    union { unsigned u; float f; } lo, hi;
    lo.u = u << 16;
    hi.u = u & 0xffff0000u;
    f32x2 r; r[0] = lo.f; r[1] = hi.f;
    return r;
}
__device__ __forceinline__ short f2b(float f) {
    __hip_bfloat16 h = __float2bfloat16(f);
    return *reinterpret_cast<short*>(&h);
}
__device__ __forceinline__ unsigned f2b2u(float x, float y) {
    __hip_bfloat162 h = __float22bfloat162_rn(make_float2(x, y));
    return *reinterpret_cast<unsigned*>(&h);
}

// -------- shared gather-mean: one wave per node, 4 edge-rows in flight, 16B/lane --------
__device__ __forceinline__ void gather_mean(const short* __restrict__ Hl,
                                            const int* __restrict__ rowptr,
                                            const int* __restrict__ adj,
                                            int node, int lane, f32x2 sum[4], float& inv) {
    int g  = lane >> 4;
    int f0 = (lane & 15) << 3;
    int beg = rowptr[node];
    int deg = rowptr[node + 1] - beg;
#pragma unroll
    for (int d = 0; d < 4; ++d) { sum[d][0] = 0.f; sum[d][1] = 0.f; }

    int av = (lane < deg) ? adj[beg + lane] : 0;
    int degc = deg < 64 ? deg : 64;

    u32x4 h0;
    bool v0 = false;
    if (degc > 0) {
        int idx = __shfl(av, g, 64);
        v0 = g < degc;
        if (v0) h0 = *(const u32x4*)(Hl + (long)idx * DIM + f0);
    }
    for (int e0 = 4; e0 < degc; e0 += 4) {
        int idx = __shfl(av, e0 + g, 64);
        bool v1 = (e0 + g) < degc;
        u32x4 h1;
        if (v1) h1 = *(const u32x4*)(Hl + (long)idx * DIM + f0);
        if (v0) {
#pragma unroll
            for (int d = 0; d < 4; ++d) sum[d] += b2f2(h0[d]);
        }
        h0 = h1; v0 = v1;
    }
    if (v0) {
#pragma unroll
        for (int d = 0; d < 4; ++d) sum[d] += b2f2(h0[d]);
    }
    for (int e0 = 64; e0 < deg; e0 += 4) {
        int e = e0 + g;
        if (e < deg) {
            int idx = adj[beg + e];
            u32x4 h = *(const u32x4*)(Hl + (long)idx * DIM + f0);
#pragma unroll
            for (int d = 0; d < 4; ++d) sum[d] += b2f2(h[d]);
        }
    }
#pragma unroll
    for (int d = 0; d < 4; ++d)
#pragma unroll
        for (int c = 0; c < 2; ++c) {
            sum[d][c] += __shfl_xor(sum[d][c], 16, 64);
            sum[d][c] += __shfl_xor(sum[d][c], 32, 64);
        }
    inv = deg > 0 ? 1.f / (float)deg : 0.f;
}

// -------- shared agg1 per-node epilogue: x1 = relu(...), emit S/T projections --------
__device__ __forceinline__ void agg1_node(const short* __restrict__ Hr,
                                          const float* __restrict__ b1,
                                          const float* __restrict__ up, const float* __restrict__ uq,
                                          const float* __restrict__ vp, const float* __restrict__ vq,
                                          float2* __restrict__ S, float2* __restrict__ T,
                                          int node, int lane, const f32x2 sum[4], float inv) {
    int f0 = (lane & 15) << 3;
    f32x4 bb0 = *(const f32x4*)(b1 + f0);
    f32x4 bb1 = *(const f32x4*)(b1 + f0 + 4);
    u32x4 hru = *(const u32x4*)(Hr + (long)node * DIM + f0);
    float x[8];
#pragma unroll
    for (int d = 0; d < 4; ++d) {
        f32x2 hr2 = b2f2(hru[d]);
        int j0 = 2 * d;
        float bias0 = (j0 < 4) ? bb0[j0] : bb1[j0 - 4];
        float bias1 = (j0 + 1 < 4) ? bb0[j0 + 1] : bb1[j0 - 3];
        x[j0]     = fmaxf(sum[d][0] * inv + hr2[0] + bias0, 0.f);
        x[j0 + 1] = fmaxf(sum[d][1] * inv + hr2[1] + bias1, 0.f);
    }
    f32x4 up0 = *(const f32x4*)(up + f0), up1 = *(const f32x4*)(up + f0 + 4);
    f32x4 uq0 = *(const f32x4*)(uq + f0), uq1 = *(const f32x4*)(uq + f0 + 4);
    f32x4 vp0 = *(const f32x4*)(vp + f0), vp1 = *(const f32x4*)(vp + f0 + 4);
    f32x4 vq0 = *(const f32x4*)(vq + f0), vq1 = *(const f32x4*)(vq + f0 + 4);
    float ap = 0.f, aq = 0.f, tp = 0.f, tq = 0.f;
#pragma unroll
    for (int j = 0; j < 8; ++j) {
        float upj = (j < 4) ? up0[j] : up1[j - 4];
        float uqj = (j < 4) ? uq0[j] : uq1[j - 4];
        float vpj = (j < 4) ? vp0[j] : vp1[j - 4];
        float vqj = (j < 4) ? vq0[j] : vq1[j - 4];
        ap += x[j] * upj;
        aq += x[j] * uqj;
        tp += x[j] * vpj;
        tq += x[j] * vqj;
    }
#pragma unroll
    for (int m = 1; m <= 8; m <<= 1) {
        ap += __shfl_xor(ap, m, 64);
        aq += __shfl_xor(aq, m, 64);
        tp += __shfl_xor(tp, m, 64);
        tq += __shfl_xor(tq, m, 64);
    }
    if (lane == 0) {
        S[node] = make_float2(ap, aq);
        T[node] = make_float2(tp, tq);
    }
}

struct Params {
    const int* ei; const int* eli; const float* emb;
    const float* W1l; const float* b1; const float* W1r;
    const float* W2l; const float* b2; const float* W2r;
    const float* Wlin; const float* blin;
    short* BT1;
    float* up; float* uq; float* vp; float* vq; float2* cpq;
    int* cnt; int* rowptr; int* widx; int* adj; int* partials;
    short* Hl; short* Hr;
    float2* S; float2* T; float* p; float* q; float* out;
};

// ================= cooperative mega-kernel (occupancy-sized grid) =================
__global__ __launch_bounds__(256, 3) void mega_k(Params P) {
    cg::grid_group grid = cg::this_grid();
    __shared__ int sbuf[512];

    const int bid  = blockIdx.x;
    const int tid  = threadIdx.x;
    const int gsz  = gridDim.x * 256;          // total threads
    const int gtid = bid * 256 + tid;
    const int lane = tid & 63;
    const int wave = tid >> 6;
    const int quad = lane >> 4;
    const int l16  = lane & 15;
    const int totWaves = gridDim.x * 4;

    // ---------- phase 0: zero cnt + prep BT1 / projections / cpq ----------
    for (int i = gtid; i < N_NODES; i += gsz) P.cnt[i] = 0;
    if (bid < 128) {
        int i = bid * 256 + tid;
        int n = i >> 7, k = i & 127;
        float v = (n < 128) ? P.W1l[k * 128 + n] : P.W1r[k * 128 + (n - 128)];
        P.BT1[n * 128 + k] = f2b(v);
    } else if (bid == 128) {
        const float* W = (tid < 128) ? P.W2l : P.W2r;
        int k = tid & 127;
        float s0 = 0.f, s1 = 0.f;
        for (int n = 0; n < 128; ++n) {
            float w = W[k * 128 + n];
            s0 += w * P.Wlin[n];
            s1 += w * P.Wlin[128 + n];
        }
        if (tid < 128) { P.up[k] = s0; P.uq[k] = s1; }
        else           { P.vp[k] = s0; P.vq[k] = s1; }
    } else if (bid == 129) {
        if (tid < 64) {
            float p0 = P.b2[tid] * P.Wlin[tid] + P.b2[tid + 64] * P.Wlin[tid + 64];
            float q0 = P.b2[tid] * P.Wlin[128 + tid] + P.b2[tid + 64] * P.Wlin[192 + tid];
#pragma unroll
            for (int m = 1; m <= 32; m <<= 1) {
                p0 += __shfl_xor(p0, m, 64);
                q0 += __shfl_xor(q0, m, 64);
            }
            if (tid == 0) *P.cpq = make_float2(p0, q0);
        }
    }
    grid.sync();

    // ---------- phase 1: count degrees ----------
    for (int e = gtid; e < N_EDGES; e += gsz) atomicAdd(&P.cnt[P.ei[N_EDGES + e]], 1);
    grid.sync();

    // ---------- phase 2: per-chunk exclusive scan ----------
    if (bid < NPARTS) {
        int i = bid * 256 + tid;
        int v = (i < N_NODES) ? P.cnt[i] : 0;
        sbuf[tid] = v;
        __syncthreads();
        for (int off = 1; off < 256; off <<= 1) {
            int x = sbuf[tid];
            int y = (tid >= off) ? sbuf[tid - off] : 0;
            __syncthreads();
            sbuf[tid] = x + y;
            __syncthreads();
        }
        if (i < N_NODES) P.rowptr[i] = sbuf[tid] - v;
        if (tid == 255) P.partials[bid] = sbuf[255];
    }
    grid.sync();

    // ---------- phase 3: apply chunk base ----------
    if (bid < NPARTS) {
        int s = 0;
        for (int t2 = tid; t2 < bid; t2 += 256) s += P.partials[t2];
#pragma unroll
        for (int m = 1; m <= 32; m <<= 1) s += __shfl_xor(s, m, 64);
        if (lane == 0) sbuf[wave] = s;
        __syncthreads();
        int base = sbuf[0] + sbuf[1] + sbuf[2] + sbuf[3];
        int i = bid * 256 + tid;
        if (i < N_NODES) {
            int r = P.rowptr[i] + base;
            P.rowptr[i] = r;
            P.widx[i] = r;
        }
        if (bid == NPARTS - 1 && tid == 0) P.rowptr[N_NODES] = base + P.partials[NPARTS - 1];
    }
    grid.sync();

    // ---------- phase 4: fill adjacency (blocks 0..127)  ||  GEMM1 (rest) ----------
    if (bid < 128) {
        for (int e = bid * 256 + tid; e < N_EDGES; e += 128 * 256) {
            int d = P.ei[N_EDGES + e];
            int pos = atomicAdd(&P.widx[d], 1);
            P.adj[pos] = P.ei[e];
        }
    } else {
        int gb = bid - 128;
        int gstride = gridDim.x - 128;
        short* __restrict__ H = (wave < 2) ? P.Hl : P.Hr;
        int fbase = (wave & 1) * 64;

        short8 Wf[4][4];
#pragma unroll
        for (int t = 0; t < 4; ++t)
#pragma unroll
            for (int kk = 0; kk < 4; ++kk)
                Wf[t][kk] = *(const short8*)(P.BT1 + (wave * 64 + t * 16 + l16) * DIM + kk * 32 + quad * 8);

        for (int s = gb; s < NT_TILES; s += gstride) {
            long arow = (long)s * 16 + l16;
            short8 xf[4];
#pragma unroll
            for (int kk = 0; kk < 4; ++kk) {
                f32x4 a0 = *(const f32x4*)(P.emb + arow * DIM + kk * 32 + quad * 8);
                f32x4 a1 = *(const f32x4*)(P.emb + arow * DIM + kk * 32 + quad * 8 + 4);
                unsigned* xu = (unsigned*)&xf[kk];
                xu[0] = f2b2u(a0[0], a0[1]);
                xu[1] = f2b2u(a0[2], a0[3]);
                xu[2] = f2b2u(a1[0], a1[1]);
                xu[3] = f2b2u(a1[2], a1[3]);
            }
            f32x4 acc[4];
#pragma unroll
            for (int t = 0; t < 4; ++t)
#pragma unroll
                for (int r = 0; r < 4; ++r) acc[t][r] = 0.f;
#pragma unroll
            for (int kk = 0; kk < 4; ++kk)
#pragma unroll
                for (int t = 0; t < 4; ++t)
                    acc[t] = __builtin_amdgcn_mfma_f32_16x16x32_bf16(Wf[t][kk], xf[kk], acc[t], 0, 0, 0);
#pragma unroll
            for (int t = 0; t < 4; ++t) {
                u32x2 o;
                o[0] = f2b2u(acc[t][0], acc[t][1]);
                o[1] = f2b2u(acc[t][2], acc[t][3]);
                *(u32x2*)(H + arow * DIM + fbase + t * 16 + quad * 4) = o;
            }
        }
    }
    grid.sync();

    // ---------- phase 5: agg1 — one wave per node (R6-proven gather) ----------
    {
        int wgid = bid * 4 + wave;
        for (int node = wgid; node < N_NODES; node += totWaves) {
            f32x2 sum[4]; float inv;
            gather_mean(P.Hl, P.rowptr, P.adj, node, lane, sum, inv);
            agg1_node(P.Hr, P.b1, P.up, P.uq, P.vp, P.vq, P.S, P.T, node, lane, sum, inv);
        }
    }
    grid.sync();

    // ---------- phase 6: agg2 ----------
    {
        int wgid = bid * 4 + wave;
        float2 c = *P.cpq;
        for (int wi = wgid; wi < N_NODES / 16; wi += totWaves) {
            int slot = lane & 3;
            int node = wi * 16 + (lane >> 2);
            int beg = P.rowptr[node], end = P.rowptr[node + 1];
            float sp = 0.f, sq = 0.f;
            for (int e = beg + slot; e < end; e += 4) {
                float2 v = P.S[P.adj[e]];
                sp += v.x; sq += v.y;
            }
            sp += __shfl_xor(sp, 1, 64); sp += __shfl_xor(sp, 2, 64);
            sq += __shfl_xor(sq, 1, 64); sq += __shfl_xor(sq, 2, 64);
            if (slot == 0) {
                int deg = end - beg;
                float inv = deg > 0 ? 1.f / (float)deg : 0.f;
                float2 t = P.T[node];
                P.p[node] = sp * inv + t.x + c.x;
                P.q[node] = sq * inv + t.y + c.y;
            }
        }
    }
    grid.sync();

    // ---------- phase 7: link predictor ----------
    {
        float bl = P.blin[0];
        for (int i = gtid; i < N_LABELS; i += gsz)
            P.out[i] = P.p[P.eli[i]] + P.q[P.eli[N_LABELS + i]] + bl;
    }
}

// ================= fallback: proven R6 multi-kernel path =================

__global__ void prep_k(const float* __restrict__ W1l, const float* __restrict__ W1r,
                       short* __restrict__ BT1,
                       const float* __restrict__ W2l, const float* __restrict__ W2r,
                       const float* __restrict__ Wlin, const float* __restrict__ b2,
                       float* __restrict__ up, float* __restrict__ uq,
                       float* __restrict__ vp, float* __restrict__ vq,
                       float2* __restrict__ cpq, int* __restrict__ cnt) {
    int b = blockIdx.x;
    int t = threadIdx.x;
    if (b < 128) {
        int i = b * 256 + t;
        int n = i >> 7, k = i & 127;
        float v = (n < 128) ? W1l[k * 128 + n] : W1r[k * 128 + (n - 128)];
        BT1[n * 128 + k] = f2b(v);
    } else if (b == 128) {
        const float* W = (t < 128) ? W2l : W2r;
        int k = t & 127;
        float s0 = 0.f, s1 = 0.f;
        for (int n = 0; n < 128; ++n) {
            float w = W[k * 128 + n];
            s0 += w * Wlin[n];
            s1 += w * Wlin[128 + n];
        }
        if (t < 128) { up[k] = s0; uq[k] = s1; }
        else         { vp[k] = s0; vq[k] = s1; }
    } else if (b == 129) {
        if (t < 64) {
            float p0 = b2[t] * Wlin[t] + b2[t + 64] * Wlin[t + 64];
            float q0 = b2[t] * Wlin[128 + t] + b2[t + 64] * Wlin[192 + t];
#pragma unroll
            for (int m = 1; m <= 32; m <<= 1) {
                p0 += __shfl_xor(p0, m, 64);
                q0 += __shfl_xor(q0, m, 64);
            }
            if (t == 0) *cpq = make_float2(p0, q0);
        }
    } else {
        int i = (b - 130) * 256 + t;
        if (i < N_NODES) cnt[i] = 0;
    }
}

__global__ void count_k(const int* __restrict__ ei, int* __restrict__ cnt) {
    int e = blockIdx.x * blockDim.x + threadIdx.x;
    if (e < N_EDGES) atomicAdd(&cnt[ei[N_EDGES + e]], 1);
}

__global__ void scan1_k(const int* __restrict__ cnt, int* __restrict__ rowptr,
                        int* __restrict__ partials) {
    __shared__ int s[256];
    int t = threadIdx.x;
    int i = blockIdx.x * 256 + t;
    int v = (i < N_NODES) ? cnt[i] : 0;
    s[t] = v;
    __syncthreads();
    for (int off = 1; off < 256; off <<= 1) {
        int x = s[t];
        int y = (t >= off) ? s[t - off] : 0;
        __syncthreads();
        s[t] = x + y;
        __syncthreads();
    }
    if (i < N_NODES) rowptr[i] = s[t] - v;
    if (t == 255) partials[blockIdx.x] = s[255];
}

__global__ void scanB_k(const int* __restrict__ partials, int* __restrict__ rowptr,
                        int* __restrict__ widx) {
    __shared__ int s[512];
    __shared__ int base_s;
    int t = threadIdx.x;
    int v = (t < NPARTS) ? partials[t] : 0;
    s[t] = v;
    __syncthreads();
    for (int off = 1; off < 512; off <<= 1) {
        int x = s[t];
        int y = (t >= off) ? s[t - off] : 0;
        __syncthreads();
        s[t] = x + y;
        __syncthreads();
    }
    int b = blockIdx.x;
    if (t == 0) base_s = (b > 0) ? s[b - 1] : 0;
    if (b == 0 && t == 0) rowptr[N_NODES] = s[NPARTS - 1];
    __syncthreads();
    if (t < 256) {
        int i = b * 256 + t;
        if (i < N_NODES) {
            int r = rowptr[i] + base_s;
            rowptr[i] = r;
            widx[i] = r;
        }
    }
}

__global__ void fill_k(const int* __restrict__ ei, int* __restrict__ widx,
                       int* __restrict__ adj) {
    int e = blockIdx.x * blockDim.x + threadIdx.x;
    if (e < N_EDGES) {
        int d = ei[N_EDGES + e];
        int pos = atomicAdd(&widx[d], 1);
        adj[pos] = ei[e];
    }
}

__global__ __launch_bounds__(256, 2) void gemm_k(const float* __restrict__ Af,
                                                 const short* __restrict__ BT,
                                                 short* __restrict__ Hl,
                                                 short* __restrict__ Hr) {
    int lane = threadIdx.x & 63;
    int wave = threadIdx.x >> 6;
    int quad = lane >> 4;
    int l16  = lane & 15;
    int half = wave & 1;
    int pair = blockIdx.x * 2 + (wave >> 1);
    const int P = GEMM_GRID * 2;

    short* __restrict__ H = half ? Hr : Hl;

    short8 Wf[8][4];
#pragma unroll
    for (int t = 0; t < 8; ++t)
#pragma unroll
        for (int kk = 0; kk < 4; ++kk)
            Wf[t][kk] = *(const short8*)(BT + (half * 128 + t * 16 + l16) * DIM + kk * 32 + quad * 8);

    for (int s = pair; s < NT_TILES; s += P) {
        long arow = (long)s * 16 + l16;
        short8 xf[4];
#pragma unroll
        for (int kk = 0; kk < 4; ++kk) {
            f32x4 a0 = *(const f32x4*)(Af + arow * DIM + kk * 32 + quad * 8);
            f32x4 a1 = *(const f32x4*)(Af + arow * DIM + kk * 32 + quad * 8 + 4);
            unsigned* xu = (unsigned*)&xf[kk];
            xu[0] = f2b2u(a0[0], a0[1]);
            xu[1] = f2b2u(a0[2], a0[3]);
            xu[2] = f2b2u(a1[0], a1[1]);
            xu[3] = f2b2u(a1[2], a1[3]);
        }
        f32x4 acc[8];
#pragma unroll
        for (int t = 0; t < 8; ++t)
#pragma unroll
            for (int r = 0; r < 4; ++r) acc[t][r] = 0.f;
#pragma unroll
        for (int kk = 0; kk < 4; ++kk)
#pragma unroll
            for (int t = 0; t < 8; ++t)
                acc[t] = __builtin_amdgcn_mfma_f32_16x16x32_bf16(Wf[t][kk], xf[kk], acc[t], 0, 0, 0);
#pragma unroll
        for (int t = 0; t < 8; ++t) {
            u32x2 o;
            o[0] = f2b2u(acc[t][0], acc[t][1]);
            o[1] = f2b2u(acc[t][2], acc[t][3]);
            *(u32x2*)(H + arow * DIM + t * 16 + quad * 4) = o;
        }
    }
}

__global__ void agg1_k(const short* __restrict__ Hl, const short* __restrict__ Hr,
                       const int* __restrict__ rowptr, const int* __restrict__ adj,
                       const float* __restrict__ b1,
                       const float* __restrict__ up, const float* __restrict__ uq,
                       const float* __restrict__ vp, const float* __restrict__ vq,
                       float2* __restrict__ S, float2* __restrict__ T) {
    int lane = threadIdx.x & 63;
    int node = blockIdx.x * 4 + (threadIdx.x >> 6);
    if (node >= N_NODES) return;
    f32x2 sum[4]; float inv;
    gather_mean(Hl, rowptr, adj, node, lane, sum, inv);
    agg1_node(Hr, b1, up, uq, vp, vq, S, T, node, lane, sum, inv);
}

__global__ void agg2_k(const int* __restrict__ rowptr, const int* __restrict__ adj,
                       const float2* __restrict__ S, const float2* __restrict__ T,
                       const float2* __restrict__ cpq,
                       float* __restrict__ p, float* __restrict__ q) {
    int lane = threadIdx.x & 63;
    int wavei = blockIdx.x * 4 + (threadIdx.x >> 6);
    int slot = lane & 3;
    int node = wavei * 16 + (lane >> 2);
    if (node >= N_NODES) return;
    int beg = rowptr[node], end = rowptr[node + 1];
    float sp = 0.f, sq = 0.f;
    for (int e = beg + slot; e < end; e += 4) {
        float2 v = S[adj[e]];
        sp += v.x; sq += v.y;
    }
    sp += __shfl_xor(sp, 1, 64); sp += __shfl_xor(sp, 2, 64);
    sq += __shfl_xor(sq, 1, 64); sq += __shfl_xor(sq, 2, 64);
    if (slot == 0) {
        int deg = end - beg;
        float inv = deg > 0 ? 1.f / (float)deg : 0.f;
        float2 t = T[node];
        float2 c = *cpq;
        p[node] = sp * inv + t.x + c.x;
        q[node] = sq * inv + t.y + c.y;
    }
}

__global__ void out_k(const int* __restrict__ eli, const float* __restrict__ p,
                      const float* __restrict__ q, const float* __restrict__ blin,
                      float* __restrict__ out) {
    int i = blockIdx.x * blockDim.x + threadIdx.x;
    if (i < N_LABELS) out[i] = p[eli[i]] + q[eli[N_LABELS + i]] + blin[0];
}

// ---------------- launch ----------------

extern "C" void kernel_launch(void* const* d_in, const int* in_sizes, int n_in,
                              void* d_out, int out_size, void* d_ws, size_t ws_size,
                              hipStream_t stream) {
    Params P;
    P.ei   = (const int*)d_in[0];
    P.eli  = (const int*)d_in[1];
    P.emb  = (const float*)d_in[2];
    P.W1l  = (const float*)d_in[3];
    P.b1   = (const float*)d_in[4];
    P.W1r  = (const float*)d_in[5];
    P.W2l  = (const float*)d_in[6];
    P.b2   = (const float*)d_in[7];
    P.W2r  = (const float*)d_in[8];
    P.Wlin = (const float*)d_in[9];
    P.blin = (const float*)d_in[10];
    P.out  = (float*)d_out;

    char* ws = (char*)d_ws;
    size_t off = 0;
    auto alloc = [&](size_t bytes) -> void* {
        off = (off + 255) & ~(size_t)255;
        void* ptr = ws + off;
        off += bytes;
        return ptr;
    };

    P.Hl  = (short*)alloc((size_t)N_NODES * DIM * 2);
    P.Hr  = (short*)alloc((size_t)N_NODES * DIM * 2);
    P.BT1 = (short*)alloc(256 * 128 * 2);
    P.up = (float*)alloc(128 * 4);
    P.uq = (float*)alloc(128 * 4);
    P.vp = (float*)alloc(128 * 4);
    P.vq = (float*)alloc(128 * 4);
    P.cpq = (float2*)alloc(8);
    P.cnt      = (int*)alloc((size_t)N_NODES * 4);
    P.rowptr   = (int*)alloc((size_t)(N_NODES + 1) * 4);
    P.widx     = (int*)alloc((size_t)N_NODES * 4);
    P.adj      = (int*)alloc((size_t)N_EDGES * 4);
    P.partials = (int*)alloc(NPARTS * 4);
    P.S        = (float2*)alloc((size_t)N_NODES * 8);
    P.T        = (float2*)alloc((size_t)N_NODES * 8);
    P.p        = (float*)alloc((size_t)N_NODES * 4);
    P.q        = (float*)alloc((size_t)N_NODES * 4);

    // occupancy-sized cooperative grid (host-side query: capture-safe, deterministic)
    int blocksPerCU = 0;
    hipError_t qerr = hipOccupancyMaxActiveBlocksPerMultiprocessor(
        &blocksPerCU, (const void*)mega_k, 256, 0);
    int coopGrid = (qerr == hipSuccess) ? blocksPerCU * 256 : 0;
    if (coopGrid > MAX_COOP_GRID) coopGrid = MAX_COOP_GRID;

    hipError_t err = hipErrorUnknown;
    if (coopGrid >= NPARTS + 1) {
        void* args[] = { (void*)&P };
        err = hipLaunchCooperativeKernel((const void*)mega_k, dim3(coopGrid), dim3(256),
                                         args, 0, stream);
    }
    if (err != hipSuccess) {
        // fallback: proven multi-kernel sequence (identical math)
        prep_k<<<130 + NPARTS, 256, 0, stream>>>(P.W1l, P.W1r, P.BT1, P.W2l, P.W2r, P.Wlin, P.b2,
                                                 P.up, P.uq, P.vp, P.vq, P.cpq, P.cnt);
        count_k<<<(N_EDGES + 255) / 256, 256, 0, stream>>>(P.ei, P.cnt);
        scan1_k<<<NPARTS, 256, 0, stream>>>(P.cnt, P.rowptr, P.partials);
        scanB_k<<<NPARTS, 512, 0, stream>>>(P.partials, P.rowptr, P.widx);
        fill_k<<<(N_EDGES + 255) / 256, 256, 0, stream>>>(P.ei, P.widx, P.adj);
        gemm_k<<<GEMM_GRID, 256, 0, stream>>>(P.emb, P.BT1, P.Hl, P.Hr);
        agg1_k<<<N_NODES / 4, 256, 0, stream>>>(P.Hl, P.Hr, P.rowptr, P.adj, P.b1,
                                                P.up, P.uq, P.vp, P.vq, P.S, P.T);
        agg2_k<<<(N_NODES + 63) / 64, 256, 0, stream>>>(P.rowptr, P.adj, P.S, P.T, P.cpq, P.p, P.q);
        out_k<<<(N_LABELS + 255) / 256, 256, 0, stream>>>(P.eli, P.p, P.q, P.blin, P.out);
    }
}

// Round 10
// 250.417 us; speedup vs baseline: 2.8187x; 2.8187x over previous
//
#include <hip/hip_runtime.h>
#include <hip/hip_bf16.h>

#define N_NODES 100000
#define N_EDGES 600000
#define N_LABELS 200000
#define DIM 128
#define NPARTS 391           // ceil(N_NODES/256)
#define NT_TILES 6250        // N_NODES / 16 exactly
#define FILL_BLOCKS 128
#define GEMM_BLOCKS 512

using short8 = __attribute__((ext_vector_type(8))) short;
using f32x2  = __attribute__((ext_vector_type(2))) float;
using f32x4  = __attribute__((ext_vector_type(4))) float;
using u32x2  = __attribute__((ext_vector_type(2))) unsigned;
using u32x4  = __attribute__((ext_vector_type(4))) unsigned;

__device__ __forceinline__ float b2f(short s) {
    union { unsigned u; float f; } c;
    c.u = ((unsigned)(unsigned short)s) << 16;
    return c.f;
}
__device__ __forceinline__ f32x2 b2f2(unsigned u) {
    union { unsigned u; float f; } lo, hi;
    lo.u = u << 16;
    hi.u = u & 0xffff0000u;
    f32x2 r; r[0] = lo.f; r[1] = hi.f;
    return r;
}
__device__ __forceinline__ short f2b(float f) {
    __hip_bfloat16 h = __float2bfloat16(f);
    return *reinterpret_cast<short*>(&h);
}
__device__ __forceinline__ unsigned f2b2u(float x, float y) {
    __hip_bfloat162 h = __float22bfloat162_rn(make_float2(x, y));
    return *reinterpret_cast<unsigned*>(&h);
}

// ---------------- prep: zero cnt + BT1 + u/v projections + cpq ----------------
__global__ void prep_k(const float* __restrict__ W1l, const float* __restrict__ W1r,
                       short* __restrict__ BT1,
                       const float* __restrict__ W2l, const float* __restrict__ W2r,
                       const float* __restrict__ Wlin, const float* __restrict__ b2,
                       float* __restrict__ up, float* __restrict__ uq,
                       float* __restrict__ vp, float* __restrict__ vq,
                       float2* __restrict__ cpq, int* __restrict__ cnt) {
    int b = blockIdx.x;
    int t = threadIdx.x;
    if (b < 128) {
        int i = b * 256 + t;                     // 32768 = 256 rows x 128 k
        int n = i >> 7, k = i & 127;
        float v = (n < 128) ? W1l[k * 128 + n] : W1r[k * 128 + (n - 128)];
        BT1[n * 128 + k] = f2b(v);
    } else if (b == 128) {
        const float* W = (t < 128) ? W2l : W2r;
        int k = t & 127;
        float s0 = 0.f, s1 = 0.f;
        for (int n = 0; n < 128; ++n) {
            float w = W[k * 128 + n];
            s0 += w * Wlin[n];
            s1 += w * Wlin[128 + n];
        }
        if (t < 128) { up[k] = s0; uq[k] = s1; }
        else         { vp[k] = s0; vq[k] = s1; }
    } else if (b == 129) {
        if (t < 64) {
            float p0 = b2[t] * Wlin[t] + b2[t + 64] * Wlin[t + 64];
            float q0 = b2[t] * Wlin[128 + t] + b2[t + 64] * Wlin[192 + t];
#pragma unroll
            for (int m = 1; m <= 32; m <<= 1) {
                p0 += __shfl_xor(p0, m, 64);
                q0 += __shfl_xor(q0, m, 64);
            }
            if (t == 0) *cpq = make_float2(p0, q0);
        }
    } else {
        int i = (b - 130) * 256 + t;
        if (i < N_NODES) cnt[i] = 0;
    }
}

// ---------------- CSR build: count + rank in one atomic pass ----------------
__global__ void count_k(const int* __restrict__ ei, int* __restrict__ cnt,
                        int* __restrict__ rank) {
    int e = blockIdx.x * blockDim.x + threadIdx.x;
    if (e < N_EDGES) rank[e] = atomicAdd(&cnt[ei[N_EDGES + e]], 1);
}

__global__ void scan1_k(const int* __restrict__ cnt, int* __restrict__ rowptr,
                        int* __restrict__ partials) {
    __shared__ int s[256];
    int t = threadIdx.x;
    int i = blockIdx.x * 256 + t;
    int v = (i < N_NODES) ? cnt[i] : 0;
    s[t] = v;
    __syncthreads();
    for (int off = 1; off < 256; off <<= 1) {
        int x = s[t];
        int y = (t >= off) ? s[t - off] : 0;
        __syncthreads();
        s[t] = x + y;
        __syncthreads();
    }
    if (i < N_NODES) rowptr[i] = s[t] - v;      // block-local exclusive
    if (t == 255) partials[blockIdx.x] = s[255];
}

// fused scan2+scan3: every block redundantly scans the partials, applies its base.
__global__ void scanB_k(const int* __restrict__ partials, int* __restrict__ rowptr) {
    __shared__ int s[512];
    __shared__ int base_s;
    int t = threadIdx.x;                         // 512 threads
    int v = (t < NPARTS) ? partials[t] : 0;
    s[t] = v;
    __syncthreads();
    for (int off = 1; off < 512; off <<= 1) {
        int x = s[t];
        int y = (t >= off) ? s[t - off] : 0;
        __syncthreads();
        s[t] = x + y;
        __syncthreads();
    }
    int b = blockIdx.x;
    if (t == 0) base_s = (b > 0) ? s[b - 1] : 0;
    if (b == 0 && t == 0) rowptr[N_NODES] = s[NPARTS - 1];
    __syncthreads();
    if (t < 256) {
        int i = b * 256 + t;
        if (i < N_NODES) rowptr[i] += base_s;
    }
}

// ---------------- fused: adjacency fill (atomic-free) || GEMM1 (weight-resident MFMA) ----------
// fill: adj[rowptr[dst] + rank[e]] = src[e]    (blocks 0..FILL_BLOCKS-1)
// gemm: [Hl|Hr] = bf16(emb) @ [W1l|W1r]        (remaining blocks)
__global__ __launch_bounds__(256, 2) void fillgemm_k(const int* __restrict__ ei,
                                                     const int* __restrict__ rank,
                                                     const int* __restrict__ rowptr,
                                                     int* __restrict__ adj,
                                                     const float* __restrict__ Af,
                                                     const short* __restrict__ BT,
                                                     short* __restrict__ Hl,
                                                     short* __restrict__ Hr) {
    if (blockIdx.x < FILL_BLOCKS) {
        for (int e = blockIdx.x * 256 + threadIdx.x; e < N_EDGES; e += FILL_BLOCKS * 256) {
            int d = ei[N_EDGES + e];
            adj[rowptr[d] + rank[e]] = ei[e];
        }
        return;
    }
    int lane = threadIdx.x & 63;
    int wave = threadIdx.x >> 6;
    int quad = lane >> 4;
    int l16  = lane & 15;
    int half = wave & 1;
    int pair = (blockIdx.x - FILL_BLOCKS) * 2 + (wave >> 1);
    const int P = GEMM_BLOCKS * 2;

    short* __restrict__ H = half ? Hr : Hl;

    short8 Wf[8][4];
#pragma unroll
    for (int t = 0; t < 8; ++t)
#pragma unroll
        for (int kk = 0; kk < 4; ++kk)
            Wf[t][kk] = *(const short8*)(BT + (half * 128 + t * 16 + l16) * DIM + kk * 32 + quad * 8);

    for (int s = pair; s < NT_TILES; s += P) {
        long arow = (long)s * 16 + l16;
        short8 xf[4];
#pragma unroll
        for (int kk = 0; kk < 4; ++kk) {
            f32x4 a0 = *(const f32x4*)(Af + arow * DIM + kk * 32 + quad * 8);
            f32x4 a1 = *(const f32x4*)(Af + arow * DIM + kk * 32 + quad * 8 + 4);
            unsigned* xu = (unsigned*)&xf[kk];
            xu[0] = f2b2u(a0[0], a0[1]);
            xu[1] = f2b2u(a0[2], a0[3]);
            xu[2] = f2b2u(a1[0], a1[1]);
            xu[3] = f2b2u(a1[2], a1[3]);
        }
        f32x4 acc[8];
#pragma unroll
        for (int t = 0; t < 8; ++t)
#pragma unroll
            for (int r = 0; r < 4; ++r) acc[t][r] = 0.f;
#pragma unroll
        for (int kk = 0; kk < 4; ++kk)
#pragma unroll
            for (int t = 0; t < 8; ++t)
                acc[t] = __builtin_amdgcn_mfma_f32_16x16x32_bf16(Wf[t][kk], xf[kk], acc[t], 0, 0, 0);
#pragma unroll
        for (int t = 0; t < 8; ++t) {
            u32x2 o;
            o[0] = f2b2u(acc[t][0], acc[t][1]);
            o[1] = f2b2u(acc[t][2], acc[t][3]);
            *(u32x2*)(H + arow * DIM + t * 16 + quad * 4) = o;
        }
    }
}

// -------- gather-mean: one wave per node, 4 edge-rows in flight, 16B/lane --------
__device__ __forceinline__ void gather_mean(const short* __restrict__ Hl,
                                            const int* __restrict__ rowptr,
                                            const int* __restrict__ adj,
                                            int node, int lane, f32x2 sum[4], float& inv) {
    int g  = lane >> 4;
    int f0 = (lane & 15) << 3;
    int beg = rowptr[node];
    int deg = rowptr[node + 1] - beg;
#pragma unroll
    for (int d = 0; d < 4; ++d) { sum[d][0] = 0.f; sum[d][1] = 0.f; }

    int av = (lane < deg) ? adj[beg + lane] : 0;
    int degc = deg < 64 ? deg : 64;

    u32x4 h0;
    bool v0 = false;
    if (degc > 0) {
        int idx = __shfl(av, g, 64);
        v0 = g < degc;
        if (v0) h0 = *(const u32x4*)(Hl + (long)idx * DIM + f0);
    }
    for (int e0 = 4; e0 < degc; e0 += 4) {
        int idx = __shfl(av, e0 + g, 64);
        bool v1 = (e0 + g) < degc;
        u32x4 h1;
        if (v1) h1 = *(const u32x4*)(Hl + (long)idx * DIM + f0);
        if (v0) {
#pragma unroll
            for (int d = 0; d < 4; ++d) sum[d] += b2f2(h0[d]);
        }
        h0 = h1; v0 = v1;
    }
    if (v0) {
#pragma unroll
        for (int d = 0; d < 4; ++d) sum[d] += b2f2(h0[d]);
    }
    for (int e0 = 64; e0 < deg; e0 += 4) {
        int e = e0 + g;
        if (e < deg) {
            int idx = adj[beg + e];
            u32x4 h = *(const u32x4*)(Hl + (long)idx * DIM + f0);
#pragma unroll
            for (int d = 0; d < 4; ++d) sum[d] += b2f2(h[d]);
        }
    }
#pragma unroll
    for (int d = 0; d < 4; ++d)
#pragma unroll
        for (int c = 0; c < 2; ++c) {
            sum[d][c] += __shfl_xor(sum[d][c], 16, 64);
            sum[d][c] += __shfl_xor(sum[d][c], 32, 64);
        }
    inv = deg > 0 ? 1.f / (float)deg : 0.f;
}

// layer-1 agg fused with layer-2 projections (packed f32x2 math in the dots)
__global__ void agg1_k(const short* __restrict__ Hl, const short* __restrict__ Hr,
                       const int* __restrict__ rowptr, const int* __restrict__ adj,
                       const float* __restrict__ b1,
                       const float* __restrict__ up, const float* __restrict__ uq,
                       const float* __restrict__ vp, const float* __restrict__ vq,
                       float2* __restrict__ S, float2* __restrict__ T) {
    int lane = threadIdx.x & 63;
    int node = blockIdx.x * 4 + (threadIdx.x >> 6);
    int f0 = (lane & 15) << 3;
    if (node >= N_NODES) return;

    f32x2 sum[4]; float inv;
    gather_mean(Hl, rowptr, adj, node, lane, sum, inv);

    u32x4 hru = *(const u32x4*)(Hr + (long)node * DIM + f0);
    f32x2 x2[4];
#pragma unroll
    for (int d = 0; d < 4; ++d) {
        f32x2 hr2 = b2f2(hru[d]);
        f32x2 bb  = *(const f32x2*)(b1 + f0 + 2 * d);
        f32x2 v   = sum[d] * inv + hr2 + bb;
        x2[d][0] = fmaxf(v[0], 0.f);
        x2[d][1] = fmaxf(v[1], 0.f);
    }

    f32x2 ap2 = {0.f, 0.f}, aq2 = {0.f, 0.f}, tp2 = {0.f, 0.f}, tq2 = {0.f, 0.f};
#pragma unroll
    for (int d = 0; d < 4; ++d) {
        f32x2 u0 = *(const f32x2*)(up + f0 + 2 * d);
        f32x2 u1 = *(const f32x2*)(uq + f0 + 2 * d);
        f32x2 w0 = *(const f32x2*)(vp + f0 + 2 * d);
        f32x2 w1 = *(const f32x2*)(vq + f0 + 2 * d);
        ap2 += x2[d] * u0;
        aq2 += x2[d] * u1;
        tp2 += x2[d] * w0;
        tq2 += x2[d] * w1;
    }
    float ap = ap2[0] + ap2[1], aq = aq2[0] + aq2[1];
    float tp = tp2[0] + tp2[1], tq = tq2[0] + tq2[1];
#pragma unroll
    for (int m = 1; m <= 8; m <<= 1) {
        ap += __shfl_xor(ap, m, 64);
        aq += __shfl_xor(aq, m, 64);
        tp += __shfl_xor(tp, m, 64);
        tq += __shfl_xor(tq, m, 64);
    }
    if (lane == 0) {
        S[node] = make_float2(ap, aq);
        T[node] = make_float2(tp, tq);
    }
}

// layer-2: p[n] = mean_nbrs(S.x) + T.x + c.x (8B gather per edge)
__global__ void agg2_k(const int* __restrict__ rowptr, const int* __restrict__ adj,
                       const float2* __restrict__ S, const float2* __restrict__ T,
                       const float2* __restrict__ cpq,
                       float* __restrict__ p, float* __restrict__ q) {
    int lane = threadIdx.x & 63;
    int wavei = blockIdx.x * 4 + (threadIdx.x >> 6);
    int slot = lane & 3;
    int node = wavei * 16 + (lane >> 2);
    if (node >= N_NODES) return;
    int beg = rowptr[node], end = rowptr[node + 1];
    float sp = 0.f, sq = 0.f;
    for (int e = beg + slot; e < end; e += 4) {
        float2 v = S[adj[e]];
        sp += v.x; sq += v.y;
    }
    sp += __shfl_xor(sp, 1, 64); sp += __shfl_xor(sp, 2, 64);
    sq += __shfl_xor(sq, 1, 64); sq += __shfl_xor(sq, 2, 64);
    if (slot == 0) {
        int deg = end - beg;
        float inv = deg > 0 ? 1.f / (float)deg : 0.f;
        float2 t = T[node];
        float2 c = *cpq;
        p[node] = sp * inv + t.x + c.x;
        q[node] = sq * inv + t.y + c.y;
    }
}

__global__ void out_k(const int* __restrict__ eli, const float* __restrict__ p,
                      const float* __restrict__ q, const float* __restrict__ blin,
                      float* __restrict__ out) {
    int i = blockIdx.x * blockDim.x + threadIdx.x;
    if (i < N_LABELS) out[i] = p[eli[i]] + q[eli[N_LABELS + i]] + blin[0];
}

// ---------------- launch ----------------

extern "C" void kernel_launch(void* const* d_in, const int* in_sizes, int n_in,
                              void* d_out, int out_size, void* d_ws, size_t ws_size,
                              hipStream_t stream) {
    const int*   edge_index = (const int*)d_in[0];
    const int*   eli        = (const int*)d_in[1];
    const float* emb        = (const float*)d_in[2];
    const float* W1l        = (const float*)d_in[3];
    const float* b1         = (const float*)d_in[4];
    const float* W1r        = (const float*)d_in[5];
    const float* W2l        = (const float*)d_in[6];
    const float* b2         = (const float*)d_in[7];
    const float* W2r        = (const float*)d_in[8];
    const float* Wlin       = (const float*)d_in[9];
    const float* blin       = (const float*)d_in[10];
    float* out = (float*)d_out;

    char* ws = (char*)d_ws;
    size_t off = 0;
    auto alloc = [&](size_t bytes) -> void* {
        off = (off + 255) & ~(size_t)255;
        void* ptr = ws + off;
        off += bytes;
        return ptr;
    };

    short* Hl  = (short*)alloc((size_t)N_NODES * DIM * 2);
    short* Hr  = (short*)alloc((size_t)N_NODES * DIM * 2);
    short* BT1 = (short*)alloc(256 * 128 * 2);
    float* up = (float*)alloc(128 * 4);
    float* uq = (float*)alloc(128 * 4);
    float* vp = (float*)alloc(128 * 4);
    float* vq = (float*)alloc(128 * 4);
    float2* cpq = (float2*)alloc(8);
    int* cnt      = (int*)alloc((size_t)N_NODES * 4);
    int* rowptr   = (int*)alloc((size_t)(N_NODES + 1) * 4);
    int* rank     = (int*)alloc((size_t)N_EDGES * 4);
    int* adj      = (int*)alloc((size_t)N_EDGES * 4);
    int* partials = (int*)alloc(NPARTS * 4);
    float2* S     = (float2*)alloc((size_t)N_NODES * 8);
    float2* T     = (float2*)alloc((size_t)N_NODES * 8);
    float* p      = (float*)alloc((size_t)N_NODES * 4);
    float* q      = (float*)alloc((size_t)N_NODES * 4);

    // prep (weights + projections + cnt zero)
    prep_k<<<130 + NPARTS, 256, 0, stream>>>(W1l, W1r, BT1, W2l, W2r, Wlin, b2,
                                             up, uq, vp, vq, cpq, cnt);
    // CSR: count + rank (single atomic pass), then scan
    count_k<<<(N_EDGES + 255) / 256, 256, 0, stream>>>(edge_index, cnt, rank);
    scan1_k<<<NPARTS, 256, 0, stream>>>(cnt, rowptr, partials);
    scanB_k<<<NPARTS, 512, 0, stream>>>(partials, rowptr);

    // adjacency fill (atomic-free) overlapped with layer-1 GEMM
    fillgemm_k<<<FILL_BLOCKS + GEMM_BLOCKS, 256, 0, stream>>>(
        edge_index, rank, rowptr, adj, emb, BT1, Hl, Hr);

    // layer-1 aggregation fused with layer-2 projections
    agg1_k<<<N_NODES / 4, 256, 0, stream>>>(Hl, Hr, rowptr, adj, b1, up, uq, vp, vq, S, T);

    // layer-2 (8B-per-edge gather) + predictor
    agg2_k<<<(N_NODES + 63) / 64, 256, 0, stream>>>(rowptr, adj, S, T, cpq, p, q);
    out_k<<<(N_LABELS + 255) / 256, 256, 0, stream>>>(eli, p, q, blin, out);
}

// Round 11
// 246.337 us; speedup vs baseline: 2.8654x; 1.0166x over previous
//
#include <hip/hip_runtime.h>
#include <hip/hip_bf16.h>

#define N_NODES 100000
#define N_EDGES 600000
#define N_LABELS 200000
#define DIM 128
#define NPARTS 391           // ceil(N_NODES/256)
#define NT_TILES 6250        // N_NODES / 16 exactly
#define FG_GRID 512          // fillgemm grid: 2/CU... with 4 blocks/CU resident, 512 = 2 rounds of 256? no: 512 blocks over 256 CUs at 4/CU capacity -> all resident

using short8 = __attribute__((ext_vector_type(8))) short;
using f32x2  = __attribute__((ext_vector_type(2))) float;
using f32x4  = __attribute__((ext_vector_type(4))) float;
using u32x2  = __attribute__((ext_vector_type(2))) unsigned;
using u32x4  = __attribute__((ext_vector_type(4))) unsigned;

__device__ __forceinline__ float b2f(short s) {
    union { unsigned u; float f; } c;
    c.u = ((unsigned)(unsigned short)s) << 16;
    return c.f;
}
__device__ __forceinline__ f32x2 b2f2(unsigned u) {
    union { unsigned u; float f; } lo, hi;
    lo.u = u << 16;
    hi.u = u & 0xffff0000u;
    f32x2 r; r[0] = lo.f; r[1] = hi.f;
    return r;
}
__device__ __forceinline__ short f2b(float f) {
    __hip_bfloat16 h = __float2bfloat16(f);
    return *reinterpret_cast<short*>(&h);
}
__device__ __forceinline__ unsigned f2b2u(float x, float y) {
    __hip_bfloat162 h = __float22bfloat162_rn(make_float2(x, y));
    return *reinterpret_cast<unsigned*>(&h);
}

// ---------------- prep: zero cnt + BT1 + u/v projections + cpq ----------------
__global__ void prep_k(const float* __restrict__ W1l, const float* __restrict__ W1r,
                       short* __restrict__ BT1,
                       const float* __restrict__ W2l, const float* __restrict__ W2r,
                       const float* __restrict__ Wlin, const float* __restrict__ b2,
                       float* __restrict__ up, float* __restrict__ uq,
                       float* __restrict__ vp, float* __restrict__ vq,
                       float2* __restrict__ cpq, int* __restrict__ cnt) {
    int b = blockIdx.x;
    int t = threadIdx.x;
    if (b < 128) {
        int i = b * 256 + t;                     // 32768 = 256 rows x 128 k
        int n = i >> 7, k = i & 127;
        float v = (n < 128) ? W1l[k * 128 + n] : W1r[k * 128 + (n - 128)];
        BT1[n * 128 + k] = f2b(v);
    } else if (b == 128) {
        const float* W = (t < 128) ? W2l : W2r;
        int k = t & 127;
        float s0 = 0.f, s1 = 0.f;
        for (int n = 0; n < 128; ++n) {
            float w = W[k * 128 + n];
            s0 += w * Wlin[n];
            s1 += w * Wlin[128 + n];
        }
        if (t < 128) { up[k] = s0; uq[k] = s1; }
        else         { vp[k] = s0; vq[k] = s1; }
    } else if (b == 129) {
        if (t < 64) {
            float p0 = b2[t] * Wlin[t] + b2[t + 64] * Wlin[t + 64];
            float q0 = b2[t] * Wlin[128 + t] + b2[t + 64] * Wlin[192 + t];
#pragma unroll
            for (int m = 1; m <= 32; m <<= 1) {
                p0 += __shfl_xor(p0, m, 64);
                q0 += __shfl_xor(q0, m, 64);
            }
            if (t == 0) *cpq = make_float2(p0, q0);
        }
    } else {
        int i = (b - 130) * 256 + t;
        if (i < N_NODES) cnt[i] = 0;
    }
}

// ---------------- CSR build: count + rank in one atomic pass ----------------
__global__ void count_k(const int* __restrict__ ei, int* __restrict__ cnt,
                        int* __restrict__ rank) {
    int e = blockIdx.x * blockDim.x + threadIdx.x;
    if (e < N_EDGES) rank[e] = atomicAdd(&cnt[ei[N_EDGES + e]], 1);
}

__global__ void scan1_k(const int* __restrict__ cnt, int* __restrict__ rowptr,
                        int* __restrict__ partials) {
    __shared__ int s[256];
    int t = threadIdx.x;
    int i = blockIdx.x * 256 + t;
    int v = (i < N_NODES) ? cnt[i] : 0;
    s[t] = v;
    __syncthreads();
    for (int off = 1; off < 256; off <<= 1) {
        int x = s[t];
        int y = (t >= off) ? s[t - off] : 0;
        __syncthreads();
        s[t] = x + y;
        __syncthreads();
    }
    if (i < N_NODES) rowptr[i] = s[t] - v;      // block-local exclusive
    if (t == 255) partials[blockIdx.x] = s[255];
}

// fused scan2+scan3: every block redundantly scans the partials, applies its base.
__global__ void scanB_k(const int* __restrict__ partials, int* __restrict__ rowptr) {
    __shared__ int s[512];
    __shared__ int base_s;
    int t = threadIdx.x;                         // 512 threads
    int v = (t < NPARTS) ? partials[t] : 0;
    s[t] = v;
    __syncthreads();
    for (int off = 1; off < 512; off <<= 1) {
        int x = s[t];
        int y = (t >= off) ? s[t - off] : 0;
        __syncthreads();
        s[t] = x + y;
        __syncthreads();
    }
    int b = blockIdx.x;
    if (t == 0) base_s = (b > 0) ? s[b - 1] : 0;
    if (b == 0 && t == 0) rowptr[N_NODES] = s[NPARTS - 1];
    __syncthreads();
    if (t < 256) {
        int i = b * 256 + t;
        if (i < N_NODES) rowptr[i] += base_s;
    }
}

// ---------------- fused: adjacency fill slice (atomic-free) + GEMM1 ----------------
// Every block: small grid-stride fill slice, then MFMA gemm. Wave w owns 64 output
// features (Wf[4][4] = 64 VGPRs resident); 4 waves cover all 256 feats of a 16-node tile.
// D layout (proven in mega_k): feature = wave*64 + t*16 + quad*4 + r, node = l16.
__global__ __launch_bounds__(256, 4) void fillgemm_k(const int* __restrict__ ei,
                                                     const int* __restrict__ rank,
                                                     const int* __restrict__ rowptr,
                                                     int* __restrict__ adj,
                                                     const float* __restrict__ Af,
                                                     const short* __restrict__ BT,
                                                     short* __restrict__ Hl,
                                                     short* __restrict__ Hr) {
    // fill slice: ~4.6 edges per thread, scattered stores, no atomics
    for (int e = blockIdx.x * 256 + threadIdx.x; e < N_EDGES; e += FG_GRID * 256) {
        int d = ei[N_EDGES + e];
        adj[rowptr[d] + rank[e]] = ei[e];
    }

    int lane = threadIdx.x & 63;
    int wave = threadIdx.x >> 6;
    int quad = lane >> 4;
    int l16  = lane & 15;
    short* __restrict__ H = (wave < 2) ? Hl : Hr;
    int fbase = (wave & 1) * 64;

    short8 Wf[4][4];
#pragma unroll
    for (int t = 0; t < 4; ++t)
#pragma unroll
        for (int kk = 0; kk < 4; ++kk)
            Wf[t][kk] = *(const short8*)(BT + (wave * 64 + t * 16 + l16) * DIM + kk * 32 + quad * 8);

    for (int s = blockIdx.x; s < NT_TILES; s += FG_GRID) {
        long arow = (long)s * 16 + l16;
        short8 xf[4];
#pragma unroll
        for (int kk = 0; kk < 4; ++kk) {
            f32x4 a0 = *(const f32x4*)(Af + arow * DIM + kk * 32 + quad * 8);
            f32x4 a1 = *(const f32x4*)(Af + arow * DIM + kk * 32 + quad * 8 + 4);
            unsigned* xu = (unsigned*)&xf[kk];
            xu[0] = f2b2u(a0[0], a0[1]);
            xu[1] = f2b2u(a0[2], a0[3]);
            xu[2] = f2b2u(a1[0], a1[1]);
            xu[3] = f2b2u(a1[2], a1[3]);
        }
        f32x4 acc[4];
#pragma unroll
        for (int t = 0; t < 4; ++t)
#pragma unroll
            for (int r = 0; r < 4; ++r) acc[t][r] = 0.f;
#pragma unroll
        for (int kk = 0; kk < 4; ++kk)
#pragma unroll
            for (int t = 0; t < 4; ++t)
                acc[t] = __builtin_amdgcn_mfma_f32_16x16x32_bf16(Wf[t][kk], xf[kk], acc[t], 0, 0, 0);
#pragma unroll
        for (int t = 0; t < 4; ++t) {
            u32x2 o;
            o[0] = f2b2u(acc[t][0], acc[t][1]);
            o[1] = f2b2u(acc[t][2], acc[t][3]);
            *(u32x2*)(H + arow * DIM + fbase + t * 16 + quad * 4) = o;
        }
    }
}

// -------- gather-mean: one wave per node, 4 edge-rows in flight, 16B/lane --------
__device__ __forceinline__ void gather_mean(const short* __restrict__ Hl,
                                            const int* __restrict__ rowptr,
                                            const int* __restrict__ adj,
                                            int node, int lane, f32x2 sum[4], float& inv) {
    int g  = lane >> 4;
    int f0 = (lane & 15) << 3;
    int beg = rowptr[node];
    int deg = rowptr[node + 1] - beg;
#pragma unroll
    for (int d = 0; d < 4; ++d) { sum[d][0] = 0.f; sum[d][1] = 0.f; }

    int av = (lane < deg) ? adj[beg + lane] : 0;
    int degc = deg < 64 ? deg : 64;

    u32x4 h0;
    bool v0 = false;
    if (degc > 0) {
        int idx = __shfl(av, g, 64);
        v0 = g < degc;
        if (v0) h0 = *(const u32x4*)(Hl + (long)idx * DIM + f0);
    }
    for (int e0 = 4; e0 < degc; e0 += 4) {
        int idx = __shfl(av, e0 + g, 64);
        bool v1 = (e0 + g) < degc;
        u32x4 h1;
        if (v1) h1 = *(const u32x4*)(Hl + (long)idx * DIM + f0);
        if (v0) {
#pragma unroll
            for (int d = 0; d < 4; ++d) sum[d] += b2f2(h0[d]);
        }
        h0 = h1; v0 = v1;
    }
    if (v0) {
#pragma unroll
        for (int d = 0; d < 4; ++d) sum[d] += b2f2(h0[d]);
    }
    for (int e0 = 64; e0 < deg; e0 += 4) {
        int e = e0 + g;
        if (e < deg) {
            int idx = adj[beg + e];
            u32x4 h = *(const u32x4*)(Hl + (long)idx * DIM + f0);
#pragma unroll
            for (int d = 0; d < 4; ++d) sum[d] += b2f2(h[d]);
        }
    }
#pragma unroll
    for (int d = 0; d < 4; ++d)
#pragma unroll
        for (int c = 0; c < 2; ++c) {
            sum[d][c] += __shfl_xor(sum[d][c], 16, 64);
            sum[d][c] += __shfl_xor(sum[d][c], 32, 64);
        }
    inv = deg > 0 ? 1.f / (float)deg : 0.f;
}

// layer-1 agg fused with layer-2 projections (packed f32x2 math in the dots)
__global__ void agg1_k(const short* __restrict__ Hl, const short* __restrict__ Hr,
                       const int* __restrict__ rowptr, const int* __restrict__ adj,
                       const float* __restrict__ b1,
                       const float* __restrict__ up, const float* __restrict__ uq,
                       const float* __restrict__ vp, const float* __restrict__ vq,
                       float2* __restrict__ S, float2* __restrict__ T) {
    int lane = threadIdx.x & 63;
    int node = blockIdx.x * 4 + (threadIdx.x >> 6);
    int f0 = (lane & 15) << 3;
    if (node >= N_NODES) return;

    f32x2 sum[4]; float inv;
    gather_mean(Hl, rowptr, adj, node, lane, sum, inv);

    u32x4 hru = *(const u32x4*)(Hr + (long)node * DIM + f0);
    f32x2 x2[4];
#pragma unroll
    for (int d = 0; d < 4; ++d) {
        f32x2 hr2 = b2f2(hru[d]);
        f32x2 bb  = *(const f32x2*)(b1 + f0 + 2 * d);
        f32x2 v   = sum[d] * inv + hr2 + bb;
        x2[d][0] = fmaxf(v[0], 0.f);
        x2[d][1] = fmaxf(v[1], 0.f);
    }

    f32x2 ap2 = {0.f, 0.f}, aq2 = {0.f, 0.f}, tp2 = {0.f, 0.f}, tq2 = {0.f, 0.f};
#pragma unroll
    for (int d = 0; d < 4; ++d) {
        f32x2 u0 = *(const f32x2*)(up + f0 + 2 * d);
        f32x2 u1 = *(const f32x2*)(uq + f0 + 2 * d);
        f32x2 w0 = *(const f32x2*)(vp + f0 + 2 * d);
        f32x2 w1 = *(const f32x2*)(vq + f0 + 2 * d);
        ap2 += x2[d] * u0;
        aq2 += x2[d] * u1;
        tp2 += x2[d] * w0;
        tq2 += x2[d] * w1;
    }
    float ap = ap2[0] + ap2[1], aq = aq2[0] + aq2[1];
    float tp = tp2[0] + tp2[1], tq = tq2[0] + tq2[1];
#pragma unroll
    for (int m = 1; m <= 8; m <<= 1) {
        ap += __shfl_xor(ap, m, 64);
        aq += __shfl_xor(aq, m, 64);
        tp += __shfl_xor(tp, m, 64);
        tq += __shfl_xor(tq, m, 64);
    }
    if (lane == 0) {
        S[node] = make_float2(ap, aq);
        T[node] = make_float2(tp, tq);
    }
}

// layer-2: p[n] = mean_nbrs(S.x) + T.x + c.x (8B gather per edge)
__global__ void agg2_k(const int* __restrict__ rowptr, const int* __restrict__ adj,
                       const float2* __restrict__ S, const float2* __restrict__ T,
                       const float2* __restrict__ cpq,
                       float* __restrict__ p, float* __restrict__ q) {
    int lane = threadIdx.x & 63;
    int wavei = blockIdx.x * 4 + (threadIdx.x >> 6);
    int slot = lane & 3;
    int node = wavei * 16 + (lane >> 2);
    if (node >= N_NODES) return;
    int beg = rowptr[node], end = rowptr[node + 1];
    float sp = 0.f, sq = 0.f;
    for (int e = beg + slot; e < end; e += 4) {
        float2 v = S[adj[e]];
        sp += v.x; sq += v.y;
    }
    sp += __shfl_xor(sp, 1, 64); sp += __shfl_xor(sp, 2, 64);
    sq += __shfl_xor(sq, 1, 64); sq += __shfl_xor(sq, 2, 64);
    if (slot == 0) {
        int deg = end - beg;
        float inv = deg > 0 ? 1.f / (float)deg : 0.f;
        float2 t = T[node];
        float2 c = *cpq;
        p[node] = sp * inv + t.x + c.x;
        q[node] = sq * inv + t.y + c.y;
    }
}

__global__ void out_k(const int* __restrict__ eli, const float* __restrict__ p,
                      const float* __restrict__ q, const float* __restrict__ blin,
                      float* __restrict__ out) {
    int i = blockIdx.x * blockDim.x + threadIdx.x;
    if (i < N_LABELS) out[i] = p[eli[i]] + q[eli[N_LABELS + i]] + blin[0];
}

// ---------------- launch ----------------

extern "C" void kernel_launch(void* const* d_in, const int* in_sizes, int n_in,
                              void* d_out, int out_size, void* d_ws, size_t ws_size,
                              hipStream_t stream) {
    const int*   edge_index = (const int*)d_in[0];
    const int*   eli        = (const int*)d_in[1];
    const float* emb        = (const float*)d_in[2];
    const float* W1l        = (const float*)d_in[3];
    const float* b1         = (const float*)d_in[4];
    const float* W1r        = (const float*)d_in[5];
    const float* W2l        = (const float*)d_in[6];
    const float* b2         = (const float*)d_in[7];
    const float* W2r        = (const float*)d_in[8];
    const float* Wlin       = (const float*)d_in[9];
    const float* blin       = (const float*)d_in[10];
    float* out = (float*)d_out;

    char* ws = (char*)d_ws;
    size_t off = 0;
    auto alloc = [&](size_t bytes) -> void* {
        off = (off + 255) & ~(size_t)255;
        void* ptr = ws + off;
        off += bytes;
        return ptr;
    };

    short* Hl  = (short*)alloc((size_t)N_NODES * DIM * 2);
    short* Hr  = (short*)alloc((size_t)N_NODES * DIM * 2);
    short* BT1 = (short*)alloc(256 * 128 * 2);
    float* up = (float*)alloc(128 * 4);
    float* uq = (float*)alloc(128 * 4);
    float* vp = (float*)alloc(128 * 4);
    float* vq = (float*)alloc(128 * 4);
    float2* cpq = (float2*)alloc(8);
    int* cnt      = (int*)alloc((size_t)N_NODES * 4);
    int* rowptr   = (int*)alloc((size_t)(N_NODES + 1) * 4);
    int* rank     = (int*)alloc((size_t)N_EDGES * 4);
    int* adj      = (int*)alloc((size_t)N_EDGES * 4);
    int* partials = (int*)alloc(NPARTS * 4);
    float2* S     = (float2*)alloc((size_t)N_NODES * 8);
    float2* T     = (float2*)alloc((size_t)N_NODES * 8);
    float* p      = (float*)alloc((size_t)N_NODES * 4);
    float* q      = (float*)alloc((size_t)N_NODES * 4);

    // prep (weights + projections + cnt zero)
    prep_k<<<130 + NPARTS, 256, 0, stream>>>(W1l, W1r, BT1, W2l, W2r, Wlin, b2,
                                             up, uq, vp, vq, cpq, cnt);
    // CSR: count + rank (single atomic pass), then scan
    count_k<<<(N_EDGES + 255) / 256, 256, 0, stream>>>(edge_index, cnt, rank);
    scan1_k<<<NPARTS, 256, 0, stream>>>(cnt, rowptr, partials);
    scanB_k<<<NPARTS, 512, 0, stream>>>(partials, rowptr);

    // adjacency fill (atomic-free slice per block) + layer-1 GEMM
    fillgemm_k<<<FG_GRID, 256, 0, stream>>>(edge_index, rank, rowptr, adj, emb, BT1, Hl, Hr);

    // layer-1 aggregation fused with layer-2 projections
    agg1_k<<<N_NODES / 4, 256, 0, stream>>>(Hl, Hr, rowptr, adj, b1, up, uq, vp, vq, S, T);

    // layer-2 (8B-per-edge gather) + predictor
    agg2_k<<<(N_NODES + 63) / 64, 256, 0, stream>>>(rowptr, adj, S, T, cpq, p, q);
    out_k<<<(N_LABELS + 255) / 256, 256, 0, stream>>>(eli, p, q, blin, out);
}